// Round 11
// baseline (680.524 us; speedup 1.0000x reference)
//
#include <hip/hip_runtime.h>
#include <hip/hip_cooperative_groups.h>

namespace cg = cooperative_groups;

typedef unsigned short u16;
typedef __bf16 bf16x8 __attribute__((ext_vector_type(8)));
typedef float f32x4 __attribute__((ext_vector_type(4)));

__device__ __forceinline__ u16 f2u(float f) {
    unsigned u = __builtin_bit_cast(unsigned, f);
    return (u16)((u + 0x7FFFu + ((u >> 16) & 1u)) >> 16);
}

__device__ __forceinline__ float u2f(u16 h) {
    return __builtin_bit_cast(float, (unsigned)h << 16);
}

__device__ __forceinline__ void glds16(const u16* g, u16* l) {
    __builtin_amdgcn_global_load_lds((const __attribute__((address_space(1))) unsigned int*)g,
                                     (__attribute__((address_space(3))) unsigned int*)l, 16, 0, 0);
}

struct MA {
    const float *x, *Wg, *bg, *Wqkv, *bqkv, *Wo, *bo, *g1l, *b1l, *g1a, *b1a, *W1, *bf1, *W2, *bf2, *g2, *b2;
    const int* ei;
    u16 *wg_t, *wqkv_t, *wo_t, *w1_t, *w2_t, *xbf, *h, *x1bf, *qkv, *xattn, *x2bf, *ffn1;
    int *cnt, *offs, *cur, *srcs;
    float *dinv, *x1, *attno, *x2, *ffno, *po, *pl, *out;
    int N, E;
};

// LN block stats; red = 8 floats of LDS scratch. Leading barrier = WAR guard on red reuse.
__device__ __forceinline__ void blk_stats(float v, float* red, float& mu, float& rstd) {
    float s1 = v, s2 = v * v;
#pragma unroll
    for (int m = 1; m < 64; m <<= 1) { s1 += __shfl_xor(s1, m, 64); s2 += __shfl_xor(s2, m, 64); }
    int lane = threadIdx.x & 63, w = threadIdx.x >> 6;
    __syncthreads();
    if (lane == 0) { red[w] = s1; red[4 + w] = s2; }
    __syncthreads();
    s1 = red[0] + red[1] + red[2] + red[3];
    s2 = red[4] + red[5] + red[6] + red[7];
    mu = s1 * (1.0f / 256.0f);
    float var = s2 * (1.0f / 256.0f) - mu * mu;
    rstd = rsqrtf(var + 1e-5f);
}

// ---- GEMM 64x64 tile, BK=128 LDS staging (exactly 32 KiB) ----
// EPI 0: f32. EPI 1: qkv (q scaled 0.125*log2e, v transposed). 2: relu->bf16. 3: bf16.
template <int EPI>
__device__ void gemm_tile(
    const u16* __restrict__ A, const u16* __restrict__ Bt, const float* __restrict__ bias,
    void* __restrict__ outp, int M, int N, int K, int bx, int by, u16* LDS) {
    u16* As = LDS;           // 64 x 128 u16 = 16 KiB
    u16* Bs = LDS + 8192;    // 16 KiB
    int tid = threadIdx.x;
    int lane = tid & 63, w = tid >> 6;
    int l15 = lane & 15, quad = lane >> 4, l7 = l15 & 7;
    int m0 = bx * 64, n0 = by * 64;
    int wm = (w >> 1) * 32, wn = (w & 1) * 32;
    f32x4 acc[2][2];
#pragma unroll
    for (int i = 0; i < 2; i++)
#pragma unroll
        for (int j = 0; j < 2; j++) acc[i][j] = f32x4{0.f, 0.f, 0.f, 0.f};

    int rA0 = (wm + l15) * 128, rA1 = (wm + 16 + l15) * 128;
    int rB0 = (wn + l15) * 128, rB1 = (wn + 16 + l15) * 128;

    for (int kb = 0; kb < K; kb += 128) {
        __syncthreads();   // WAR: previous round/unit finished reading LDS
#pragma unroll
        for (int i = 0; i < 4; i++) {
            int s = i * 256 + tid;
            int j = s >> 4, c = (s & 15) ^ (j & 7);   // XOR low 3 bits of chunk
            glds16(A + (long)(m0 + j) * K + kb + c * 8, &As[s * 8]);
            glds16(Bt + (long)(n0 + j) * K + kb + c * 8, &Bs[s * 8]);
        }
        __syncthreads();
#pragma unroll
        for (int step = 0; step < 4; step++) {
            int ch = (step << 2) + quad;              // 0..15
            int d8 = ((ch & 8) | ((ch & 7) ^ l7)) << 3;
            bf16x8 af0 = *(const bf16x8*)&As[rA0 + d8];
            bf16x8 af1 = *(const bf16x8*)&As[rA1 + d8];
            bf16x8 bf0 = *(const bf16x8*)&Bs[rB0 + d8];
            bf16x8 bf1 = *(const bf16x8*)&Bs[rB1 + d8];
            acc[0][0] = __builtin_amdgcn_mfma_f32_16x16x32_bf16(af0, bf0, acc[0][0], 0, 0, 0);
            acc[0][1] = __builtin_amdgcn_mfma_f32_16x16x32_bf16(af0, bf1, acc[0][1], 0, 0, 0);
            acc[1][0] = __builtin_amdgcn_mfma_f32_16x16x32_bf16(af1, bf0, acc[1][0], 0, 0, 0);
            acc[1][1] = __builtin_amdgcn_mfma_f32_16x16x32_bf16(af1, bf1, acc[1][1], 0, 0, 0);
        }
    }

#pragma unroll
    for (int nf = 0; nf < 2; nf++) {
        int col = n0 + wn + nf * 16 + l15;
        float bv = bias ? bias[col] : 0.0f;
#pragma unroll
        for (int mf = 0; mf < 2; mf++) {
#pragma unroll
            for (int r = 0; r < 4; r++) {
                int row = m0 + wm + mf * 16 + quad * 4 + r;
                float v = acc[mf][nf][r] + bv;
                if (EPI == 0) {
                    ((float*)outp)[(long)row * N + col] = v;
                } else if (EPI == 1) {
                    u16* q = (u16*)outp;
                    u16* kk = q + (long)M * 256;
                    u16* vt = kk + (long)M * 256;
                    if (col < 256) {
                        q[(((col >> 6) * (long)M) + row) * 64 + (col & 63)] = f2u(v * 0.180336884f);
                    } else if (col < 512) {
                        int c = col - 256;
                        kk[(((c >> 6) * (long)M) + row) * 64 + (c & 63)] = f2u(v);
                    } else {
                        int c = col - 512;
                        vt[((c >> 6) * 64 + (c & 63)) * (long)M + row] = f2u(v);
                    }
                } else if (EPI == 2) {
                    ((u16*)outp)[(long)row * N + col] = f2u(v > 0.f ? v : 0.f);
                } else {
                    ((u16*)outp)[(long)row * N + col] = f2u(v);
                }
            }
        }
    }
}

// ---- one attention unit (S=4 split-K), single-buffered KV (24 KiB of LDS) ----
__device__ void attn_unit(const MA& a, int u, u16* LDS) {
    int N = a.N;
    const int S = 4;
    int t = threadIdx.x;
    int w = t >> 6, lane = t & 63, l15 = lane & 15, quad = lane >> 4;
    int hs = u & 15, hh = hs & 3, sp = hs >> 2, qb = u >> 4;
    int q0 = qb * 64 + w * 16;
    int kbeg = sp * (N / S);
    int nit = (N / S) / 64;
    const u16* qh = a.qkv + (long)hh * N * 64;
    const u16* kh = a.qkv + (long)N * 256 + (long)hh * N * 64;
    const u16* vh = a.qkv + (long)2 * N * 256 + (long)hh * 64 * N;
    u16* KV = LDS;                 // K: [0,4096) u16, V: [4096,8192)
    u16* Pw = LDS + 8192 + w * 1024;

    int s0 = t, j0 = s0 >> 3, c0s = ((s0 & 7) ^ (j0 & 7)) * 8;
    int s1 = t + 256, j1 = s1 >> 3, c1s = ((s1 & 7) ^ (j1 & 7)) * 8;
    const u16* kp0 = kh + (long)(kbeg + j0) * 64 + c0s;
    const u16* kp1 = kh + (long)(kbeg + j1) * 64 + c1s;
    const u16* vp0 = vh + (long)j0 * N + kbeg + c0s;
    const u16* vp1 = vh + (long)j1 * N + kbeg + c1s;
    u16* lk0 = KV + s0 * 8;
    u16* lk1 = KV + s1 * 8;
    u16* lv0 = KV + 4096 + s0 * 8;
    u16* lv1 = KV + 4096 + s1 * 8;

    int lo3 = l15 & 7;
    int c0 = (quad ^ lo3) * 8;
    int c1 = c0 ^ 32;
    int ps = lo3 << 1;
    int pw0 = l15 * 64 + (((quad << 1) ^ ps) << 2);
    int pw1 = l15 * 64 + (((8 + (quad << 1)) ^ ps) << 2);
    int pca[4];
#pragma unroll
    for (int nt = 0; nt < 4; nt++) pca[nt] = l15 * 64 + (((nt * 4 + quad) ^ ps) << 2);

    bf16x8 aq0 = *(const bf16x8*)(qh + (long)(q0 + l15) * 64 + quad * 8);
    bf16x8 aq1 = *(const bf16x8*)(qh + (long)(q0 + l15) * 64 + 32 + quad * 8);
    bf16x8 ones;
#pragma unroll
    for (int i = 0; i < 8; i++) ones[i] = (__bf16)1.0f;

    f32x4 o[4];
#pragma unroll
    for (int dn = 0; dn < 4; dn++) o[dn] = f32x4{0.f, 0.f, 0.f, 0.f};
    f32x4 accl = f32x4{0.f, 0.f, 0.f, 0.f};

    for (int it = 0; it < nit; it++) {
        // previous iteration/unit finished all LDS reads (trailing barrier below)
        glds16(kp0, lk0); glds16(kp1, lk1);
        glds16(vp0, lv0); glds16(vp1, lv1);
        kp0 += 4096; kp1 += 4096; vp0 += 64; vp1 += 64;
        __syncthreads();   // vmcnt drained; staged tile visible
#pragma unroll
        for (int nt = 0; nt < 4; nt++) {
            const u16* Kr = KV + (nt * 16 + l15) * 64;
            bf16x8 kf0 = *(const bf16x8*)(Kr + c0);
            bf16x8 kf1 = *(const bf16x8*)(Kr + c1);
            f32x4 s = f32x4{0.f, 0.f, 0.f, 0.f};
            s = __builtin_amdgcn_mfma_f32_16x16x32_bf16(kf0, aq0, s, 0, 0, 0);  // C[key][query]
            s = __builtin_amdgcn_mfma_f32_16x16x32_bf16(kf1, aq1, s, 0, 0, 0);
            unsigned u0 = (unsigned)((int)(s[0] * 8388608.0f) + 1064992209);
            unsigned u1 = (unsigned)((int)(s[1] * 8388608.0f) + 1064992209);
            unsigned u2 = (unsigned)((int)(s[2] * 8388608.0f) + 1064992209);
            unsigned u3 = (unsigned)((int)(s[3] * 8388608.0f) + 1064992209);
            unsigned pk01 = __builtin_amdgcn_perm(u1, u0, 0x07060302u);
            unsigned pk23 = __builtin_amdgcn_perm(u3, u2, 0x07060302u);
            *(uint2*)&Pw[pca[nt]] = uint2{pk01, pk23};
        }
        bf16x8 pa0 = *(const bf16x8*)&Pw[pw0];
        bf16x8 pa1 = *(const bf16x8*)&Pw[pw1];
        accl = __builtin_amdgcn_mfma_f32_16x16x32_bf16(pa0, ones, accl, 0, 0, 0);
        accl = __builtin_amdgcn_mfma_f32_16x16x32_bf16(pa1, ones, accl, 0, 0, 0);
#pragma unroll
        for (int dn = 0; dn < 4; dn++) {
            const u16* Vr = KV + 4096 + (dn * 16 + l15) * 64;
            bf16x8 v0 = *(const bf16x8*)(Vr + c0);
            bf16x8 v1 = *(const bf16x8*)(Vr + c1);
            o[dn] = __builtin_amdgcn_mfma_f32_16x16x32_bf16(pa0, v0, o[dn], 0, 0, 0);
            o[dn] = __builtin_amdgcn_mfma_f32_16x16x32_bf16(pa1, v1, o[dn], 0, 0, 0);
        }
        __syncthreads();   // all reads done before next stage overwrites
    }

    long pbase = ((long)(sp * 4 + hh)) * N;
#pragma unroll
    for (int dn = 0; dn < 4; dn++)
#pragma unroll
        for (int r = 0; r < 4; r++) {
            int row = q0 + quad * 4 + r;
            a.po[(pbase + row) * 64 + dn * 16 + l15] = o[dn][r];
        }
    if (l15 == 0) {
#pragma unroll
        for (int r = 0; r < 4; r++) a.pl[pbase + q0 + quad * 4 + r] = accl[r];
    }
}

// ---- one phase of the pipeline; grid-stride over work units; NB = gridDim.x ----
__device__ void phase_run(const MA& a, int ph, u16* LDS) {
    int b = blockIdx.x, t = threadIdx.x, NB = gridDim.x;
    int N = a.N, E = a.E;
    int nt64 = N / 64;
    float* red = (float*)LDS;

    switch (ph) {
    case 0: {  // weight transposes (144) + x cvt + cnt zero
        int xb = (N * 256) / 4096, U = 144 + xb + N / 256;
        for (int u = b; u < U; u += NB) {
            if (u < 144) {
                const float* in; u16* out; int R, C, tb;
                if (u < 16)       { in = a.Wg;   out = a.wg_t;   R = 256; C = 256; tb = u; }
                else if (u < 64)  { in = a.Wqkv; out = a.wqkv_t; R = 256; C = 768; tb = u - 16; }
                else if (u < 80)  { in = a.Wo;   out = a.wo_t;   R = 256; C = 256; tb = u - 64; }
                else if (u < 112) { in = a.W1;   out = a.w1_t;   R = 256; C = 512; tb = u - 80; }
                else              { in = a.W2;   out = a.w2_t;   R = 512; C = 256; tb = u - 112; }
                int tcols = C >> 6;
                int tr = tb / tcols, tc = tb - tr * tcols;
                float* T = (float*)LDS;            // 64 x 65 f32
                int i0 = t >> 6, j = t & 63;
                __syncthreads();                    // WAR on T reuse
#pragma unroll
                for (int p = 0; p < 16; p++) {
                    int r = p * 4 + i0;
                    T[r * 65 + j] = in[(long)(tr * 64 + r) * C + tc * 64 + j];
                }
                __syncthreads();
#pragma unroll
                for (int p = 0; p < 16; p++) {
                    int c = p * 4 + i0;
                    out[(long)(tc * 64 + c) * R + tr * 64 + j] = f2u(T[j * 65 + c]);
                }
            } else if (u < 144 + xb) {
                long base = (long)(u - 144) * 4096;
#pragma unroll
                for (int p = 0; p < 4; p++) {
                    long idx = base + p * 1024 + t * 4;
                    float4 v = *(const float4*)&a.x[idx];
                    unsigned lo = (unsigned)f2u(v.x) | ((unsigned)f2u(v.y) << 16);
                    unsigned hi = (unsigned)f2u(v.z) | ((unsigned)f2u(v.w) << 16);
                    *(uint2*)&a.xbf[idx] = uint2{lo, hi};
                }
            } else {
                a.cnt[(u - 144 - xb) * 256 + t] = 0;
            }
        }
        break;
    }
    case 1:
        for (int e = b * 256 + t; e < E; e += NB * 256) atomicAdd(&a.cnt[a.ei[E + e]], 1);
        break;
    case 2:
        if (b == 0) {
            int* sums = (int*)LDS;
            int base = t * 16;
            int loc[16]; int s = 0;
#pragma unroll
            for (int i = 0; i < 16; i++) { loc[i] = s; s += a.cnt[base + i]; }
            sums[t] = s;
            __syncthreads();
            for (int off = 1; off < 256; off <<= 1) {
                int v = (t >= off) ? sums[t - off] : 0;
                __syncthreads();
                sums[t] += v;
                __syncthreads();
            }
            int ex = (t == 0) ? 0 : sums[t - 1];
#pragma unroll
            for (int i = 0; i < 16; i++) {
                int o = ex + loc[i];
                a.offs[base + i] = o; a.cur[base + i] = o;
                a.dinv[base + i] = rsqrtf((float)(a.cnt[base + i] + 1));
            }
        }
        break;
    case 3: {  // h = x @ Wg + CSR scatter
        int gt = nt64 * 4, eb = E / 256;
        for (int u = b; u < gt + eb; u += NB) {
            if (u < gt) {
                gemm_tile<3>(a.xbf, a.wg_t, nullptr, a.h, N, 256, 256, u % nt64, u / nt64, LDS);
            } else {
                int e = (u - gt) * 256 + t;
                if (e < E) {
                    int s = a.ei[e], d = a.ei[E + e];
                    int p = atomicAdd(&a.cur[d], 1);
                    a.srcs[p] = s;
                }
            }
        }
        break;
    }
    case 4:
        for (int n = b; n < N; n += NB) {
            int d = t;
            int c = a.cnt[n], st = a.offs[n];
            float dn = a.dinv[n];
            float agg = u2f(a.h[(long)n * 256 + d]) * dn;
            int e = 0;
            for (; e + 4 <= c; e += 4) {
                int s0 = a.srcs[st + e], s1 = a.srcs[st + e + 1], s2 = a.srcs[st + e + 2], s3 = a.srcs[st + e + 3];
                float a0 = u2f(a.h[(long)s0 * 256 + d]) * a.dinv[s0];
                float a1 = u2f(a.h[(long)s1 * 256 + d]) * a.dinv[s1];
                float a2 = u2f(a.h[(long)s2 * 256 + d]) * a.dinv[s2];
                float a3 = u2f(a.h[(long)s3 * 256 + d]) * a.dinv[s3];
                agg += (a0 + a1) + (a2 + a3);
            }
            for (; e < c; e++) {
                int s = a.srcs[st + e];
                agg += u2f(a.h[(long)s * 256 + d]) * a.dinv[s];
            }
            float v = a.x[(long)n * 256 + d] + dn * agg + a.bg[d];
            float mu, rs;
            blk_stats(v, red, mu, rs);
            float y = (v - mu) * rs * a.g1l[d] + a.b1l[d];
            a.x1[(long)n * 256 + d] = y;
            a.x1bf[(long)n * 256 + d] = f2u(y);
        }
        break;
    case 5:
        for (int u = b; u < nt64 * 12; u += NB)
            gemm_tile<1>(a.x1bf, a.wqkv_t, a.bqkv, a.qkv, N, 768, 256, u % nt64, u / nt64, LDS);
        break;
    case 6:
        for (int u = b; u < nt64 * 16; u += NB) attn_unit(a, u, LDS);
        break;
    case 7:
        for (int n = b; n < N; n += NB) {
            int hh = t >> 6, d = t & 63;
            float osum = 0.f, lsum = 0.f;
#pragma unroll
            for (int s = 0; s < 4; s++) {
                osum += a.po[(((long)(s * 4 + hh)) * N + n) * 64 + d];
                lsum += a.pl[((long)(s * 4 + hh)) * N + n];
            }
            a.xattn[(long)n * 256 + t] = f2u(osum / lsum);
        }
        break;
    case 8:
        for (int u = b; u < nt64 * 4; u += NB)
            gemm_tile<0>(a.xattn, a.wo_t, a.bo, a.attno, N, 256, 256, u % nt64, u / nt64, LDS);
        break;
    case 9:
        for (int n = b; n < N; n += NB) {
            long idx = (long)n * 256 + t;
            float v = a.x1[idx] + a.attno[idx];
            float mu, rs;
            blk_stats(v, red, mu, rs);
            float y = (v - mu) * rs * a.g1a[t] + a.b1a[t];
            a.x2[idx] = y;
            a.x2bf[idx] = f2u(y);
        }
        break;
    case 10:
        for (int u = b; u < nt64 * 8; u += NB)
            gemm_tile<2>(a.x2bf, a.w1_t, a.bf1, a.ffn1, N, 512, 256, u % nt64, u / nt64, LDS);
        break;
    case 11:
        for (int u = b; u < nt64 * 4; u += NB)
            gemm_tile<0>(a.ffn1, a.w2_t, a.bf2, a.ffno, N, 256, 512, u % nt64, u / nt64, LDS);
        break;
    case 12:
        for (int n = b; n < N; n += NB) {
            long idx = (long)n * 256 + t;
            float v = a.x2[idx] + a.ffno[idx];
            float mu, rs;
            blk_stats(v, red, mu, rs);
            a.out[idx] = (v - mu) * rs * a.g2[t] + a.b2[t];
        }
        break;
    }
}

// ---- cooperative megakernel: 13 phases, 12 grid syncs, 32 KiB LDS ----
__global__ __launch_bounds__(256, 2) void mega_k(MA a) {
    cg::grid_group grid = cg::this_grid();
    __shared__ __align__(16) u16 LDS[16384];   // 32 KiB
    for (int ph = 0; ph < 13; ph++) {
        phase_run(a, ph, LDS);
        if (ph < 12) grid.sync();
    }
}

// ---- fallback: same phases as 13 ordinary launches ----
__global__ __launch_bounds__(256) void phase_k(MA a, int ph) {
    __shared__ __align__(16) u16 LDS[16384];
    phase_run(a, ph, LDS);
}

// ---------------- launcher ----------------

extern "C" void kernel_launch(void* const* d_in, const int* in_sizes, int n_in,
                              void* d_out, int out_size, void* d_ws, size_t ws_size,
                              hipStream_t stream) {
    int N = in_sizes[0] / 256;  // 4096
    int E = in_sizes[1] / 2;    // 131072
    const int S = 4;

    char* p = (char*)d_ws;
    auto alloc = [&](size_t bytes) { void* r = (void*)p; p += (bytes + 255) & ~(size_t)255; return r; };

    MA a;
    a.x    = (const float*)d_in[0];
    a.ei   = (const int*)d_in[1];
    a.Wg   = (const float*)d_in[2];
    a.bg   = (const float*)d_in[3];
    a.Wqkv = (const float*)d_in[4];
    a.bqkv = (const float*)d_in[5];
    a.Wo   = (const float*)d_in[6];
    a.bo   = (const float*)d_in[7];
    a.g1l  = (const float*)d_in[8];
    a.b1l  = (const float*)d_in[9];
    a.g1a  = (const float*)d_in[10];
    a.b1a  = (const float*)d_in[11];
    a.W1   = (const float*)d_in[12];
    a.bf1  = (const float*)d_in[13];
    a.W2   = (const float*)d_in[14];
    a.bf2  = (const float*)d_in[15];
    a.g2   = (const float*)d_in[16];
    a.b2   = (const float*)d_in[17];
    a.out  = (float*)d_out;
    a.N = N; a.E = E;

    a.wg_t   = (u16*)alloc((size_t)256 * 256 * 2);
    a.wqkv_t = (u16*)alloc((size_t)256 * 768 * 2);
    a.wo_t   = (u16*)alloc((size_t)256 * 256 * 2);
    a.w1_t   = (u16*)alloc((size_t)512 * 256 * 2);
    a.w2_t   = (u16*)alloc((size_t)256 * 512 * 2);
    a.xbf    = (u16*)alloc((size_t)N * 256 * 2);
    a.h      = (u16*)alloc((size_t)N * 256 * 2);
    a.cnt    = (int*)alloc((size_t)N * 4);
    a.offs   = (int*)alloc((size_t)N * 4);
    a.cur    = (int*)alloc((size_t)N * 4);
    a.dinv   = (float*)alloc((size_t)N * 4);
    a.srcs   = (int*)alloc((size_t)E * 4);
    a.x1     = (float*)alloc((size_t)N * 256 * 4);
    a.x1bf   = (u16*)alloc((size_t)N * 256 * 2);
    a.qkv    = (u16*)alloc((size_t)3 * N * 256 * 2);
    a.xattn  = (u16*)alloc((size_t)N * 256 * 2);
    a.attno  = (float*)alloc((size_t)N * 256 * 4);
    a.x2     = (float*)alloc((size_t)N * 256 * 4);
    a.x2bf   = (u16*)alloc((size_t)N * 256 * 2);
    a.ffn1   = (u16*)alloc((size_t)N * 512 * 2);
    a.ffno   = (float*)alloc((size_t)N * 256 * 4);
    a.po     = (float*)alloc((size_t)S * 4 * N * 64 * 4);
    a.pl     = (float*)alloc((size_t)S * 4 * N * 4);

    // size grid from the runtime's own occupancy model (deterministic every call)
    int maxB = 0;
    hipError_t oe = hipOccupancyMaxActiveBlocksPerMultiprocessor(&maxB, mega_k, 256, 0);
    int NB = maxB * 256;          // 256 CUs on MI355X
    if (NB > 1024) NB = 1024;

    hipError_t le = hipErrorUnknown;
    if (oe == hipSuccess && NB >= 256) {
        void* kp[] = {(void*)&a};
        le = hipLaunchCooperativeKernel(mega_k, dim3(NB), dim3(256), kp, 0, stream);
    }
    if (le != hipSuccess) {
        // fallback: identical phases as ordinary launches
        for (int ph = 0; ph < 13; ph++)
            phase_k<<<1024, 256, 0, stream>>>(a, ph);
    }
}